// Round 7
// baseline (203.205 us; speedup 1.0000x reference)
//
#include <hip/hip_runtime.h>
#include <cstdint>
#include <cstddef>

#define N 4096
#define M 4096
#define DT 0.01f

#define BMW 128       // block rows (j)
#define BNW 256       // block cols (i)
#define TILE3 49152   // per-tile LDS: A 128x64 bf16 (16 KB) + B 256x64 bf16 (32 KB)

typedef short bf16x8 __attribute__((ext_vector_type(8)));
typedef float f32x4 __attribute__((ext_vector_type(4)));

__device__ __forceinline__ unsigned short f2bf(float f) {
  unsigned u = __builtin_bit_cast(unsigned, f);
  return (unsigned short)((u + 0x7fffu + ((u >> 16) & 1u)) >> 16);  // RNE
}

// Fused prep. Blocks [0,4096): exp-transpose tiles -> kbT[i*N+l]=bf16(exp(-x[l*M+i])).
// Blocks [4096,8192): weighted Toeplitz row j: Tm[j*N+l] = w*h[j-l] (l<=j else 0),
// w = 1 + 0.5*[l==j] - 0.5*[l==0]   =>   out = fe[j] - dt*(Tm @ k)[j,i].
__global__ __launch_bounds__(256)
void prep_kernel(const float* __restrict__ x, const float* __restrict__ h,
                 unsigned short* __restrict__ kbT, unsigned short* __restrict__ Tm) {
  __shared__ __align__(16) unsigned short smem[64 * 66];  // 8448 B, both modes
  const int bid = (int)blockIdx.x;
  const int tid = threadIdx.x;

  if (bid < 4096) {
    // ---- exp-transpose 64x64 tile ----
    unsigned short (*tileT)[66] = (unsigned short(*)[66])smem;  // [i][l]
    const int i0 = (bid & 63) * 64, l0 = (bid >> 6) * 64;
    const int ci = (tid & 15) * 4;
    const int r0 = tid >> 4;
#pragma unroll
    for (int rr = 0; rr < 4; ++rr) {
      const int l = l0 + r0 + rr * 16;
      const float4 xv = *reinterpret_cast<const float4*>(&x[(size_t)l * M + i0 + ci]);
      const int lr = r0 + rr * 16;
      tileT[ci + 0][lr] = f2bf(__expf(-xv.x));
      tileT[ci + 1][lr] = f2bf(__expf(-xv.y));
      tileT[ci + 2][lr] = f2bf(__expf(-xv.z));
      tileT[ci + 3][lr] = f2bf(__expf(-xv.w));
    }
    __syncthreads();
    const int ir = tid >> 2, cc = tid & 3;
#pragma unroll
    for (int s = 0; s < 2; ++s) {
      const int ch = cc + s * 4;
      bf16x8 v = *reinterpret_cast<const bf16x8*>(&tileT[ir][ch * 8]);
      *reinterpret_cast<bf16x8*>(&kbT[(size_t)(i0 + ir) * N + l0 + ch * 8]) = v;
    }
  } else {
    // ---- Toeplitz row j ----
    const int j = bid - 4096;
    unsigned short* hb = smem;  // hb[0..4095] = bf16(h[.])
#pragma unroll
    for (int p = 0; p < 4; ++p) {
      const int idx = p * 1024 + tid * 4;
      const float4 hv = *reinterpret_cast<const float4*>(&h[idx]);
      ushort4 pk;
      pk.x = f2bf(hv.x); pk.y = f2bf(hv.y); pk.z = f2bf(hv.z); pk.w = f2bf(hv.w);
      *reinterpret_cast<ushort4*>(&hb[idx]) = pk;
    }
    __syncthreads();
    const int l0 = tid * 16;
    unsigned short v[16];
#pragma unroll
    for (int s = 0; s < 16; ++s) {
      const int l = l0 + s;
      unsigned short r = 0;
      if (l <= j) {
        const float w = 1.0f + (l == j ? 0.5f : 0.0f) - (l == 0 ? 0.5f : 0.0f);
        float hv = __builtin_bit_cast(float, (unsigned)hb[j - l] << 16);
        r = f2bf(w * hv);
      }
      v[s] = r;
    }
#pragma unroll
    for (int half = 0; half < 2; ++half) {
      uint4 pk;
      const unsigned short* q = &v[half * 8];
      pk.x = (unsigned)q[0] | ((unsigned)q[1] << 16);
      pk.y = (unsigned)q[2] | ((unsigned)q[3] << 16);
      pk.z = (unsigned)q[4] | ((unsigned)q[5] << 16);
      pk.w = (unsigned)q[6] | ((unsigned)q[7] << 16);
      *reinterpret_cast<uint4*>(&Tm[(size_t)j * N + l0 + half * 8]) = pk;
    }
  }
}

__device__ __forceinline__ void gld16(void* lds, const void* g) {
  __builtin_amdgcn_global_load_lds(
      (const __attribute__((address_space(1))) void*)g,
      (__attribute__((address_space(3))) void*)lds, 16, 0, 0);
}

// Paired triangular GEMM, 4-wave / register-double-buffered fragments:
//  - Block 128x256, 4 waves (1 per SIMD), wave tile 64x128 -> per K-64 tile the
//    block issues only 96 ds_read_b128 (vs 128 for 8-wave 64x64): LDS ~1730 cyc
//    vs MFMA 1242 cyc/SIMD.
//  - Overlap via intra-wave ILP: fragments double-buffered in registers; the 12
//    ds_reads for the NEXT K-32 half are issued before each 32-MFMA cluster, so
//    the LDS pipe runs under the MFMA pipe (no wave-mate needed at 1 wave/SIMD,
//    VGPR budget ~512 so ~250 regs is safe).
//  - BK=64 (128-B rows) restores the PROVEN conflict-free XOR(row&7) swizzle
//    (BK=32/64-B rows measured 6.5M conflicts in round 5 -> reverted).
//  - 3 tile buffers (144 KB). Boundary t: vmcnt(0) [certifies tiles t, t+1 --
//    newest in-flight stage was issued a full tile (~1700 cyc) earlier] ->
//    s_barrier -> stage(t+2). One barrier + one vmcnt per K-64 tile.
// Grid 16 cols x 16 pairs (p, 31-p): every block runs exactly 68 K-tiles.
__global__ __launch_bounds__(256, 1)
void gemm_tri_kernel(const unsigned short* __restrict__ Tm,
                     const unsigned short* __restrict__ Bt,
                     const float* __restrict__ fe,
                     float* __restrict__ out) {
  __shared__ __align__(16) char sm[3 * TILE3];  // 144 KB

  const int tid = threadIdx.x;
  const int wave = tid >> 6, lane = tid & 63;
  const int wr = wave >> 1, wcol = wave & 1;   // 2x2 wave grid of 64x128 tiles
  const int lo16 = lane & 15, hi4 = lane >> 4;
  const int sw = lane & 7;                     // swizzle key (== row&7 for this lane's rows)
  const int i0 = blockIdx.x * BNW;
  const int p = (int)blockIdx.y;

  const size_t strideB = (size_t)N * 2;        // 8192 B per matrix row

  // staging: 256 threads cover 32 rows x 8 chunks of 16 B per pass
  const int srow = tid >> 3;                   // row within a 32-row pass
  const int gq = ((tid & 7) ^ (srow & 7)) * 16;  // pre-swizzled global chunk

  // stage K-tile t (A: 4 passes, B: 8 passes = 12 gld16/thread)
  auto stage = [&](int j0s, int t, int b) {
    char* dst = (char*)sm + b * TILE3 + tid * 16;
    const char* Asrc = (const char*)Tm + (size_t)(j0s + srow) * strideB + (size_t)t * 128 + gq;
#pragma unroll
    for (int pp = 0; pp < 4; ++pp)
      gld16(dst + pp * 4096, Asrc + (size_t)pp * 32 * strideB);
    const char* Bsrc = (const char*)Bt + (size_t)(i0 + srow) * strideB + (size_t)t * 128 + gq;
    char* dstB = dst + 16384;
#pragma unroll
    for (int pp = 0; pp < 8; ++pp)
      gld16(dstB + pp * 4096, Bsrc + (size_t)pp * 32 * strideB);
  };

  auto rdA = [&](bf16x8* f, const char* Ab, int h) {
    const int q = (((h << 2) + hi4) ^ sw) << 4;
#pragma unroll
    for (int mt = 0; mt < 4; ++mt)
      f[mt] = *reinterpret_cast<const bf16x8*>(Ab + (wr * 64 + mt * 16 + lo16) * 128 + q);
  };
  auto rdB = [&](bf16x8* f, const char* Bb, int h) {
    const int q = (((h << 2) + hi4) ^ sw) << 4;
#pragma unroll
    for (int nt = 0; nt < 8; ++nt)
      f[nt] = *reinterpret_cast<const bf16x8*>(Bb + (wcol * 128 + nt * 16 + lo16) * 128 + q);
  };

#pragma unroll 1
  for (int ph = 0; ph < 2; ++ph) {
    const int by = ph ? (31 - p) : p;
    const int j0 = by * BMW;
    const int nIter = 2 * by + 2;  // causal bound: K <= 128*(by+1)

    f32x4 acc[4][8] = {};
    bf16x8 a0[4], b0[8], a1[4], b1[8];

    // prologue: stage tiles 0 and 1
    stage(j0, 0, 0);
    stage(j0, 1, 1);

    int bcur = 0;
#pragma unroll 1
    for (int t = 0; t < nIter; ++t) {
      // boundary t: everything staged so far (incl. tile t+1) has landed
      asm volatile("s_waitcnt vmcnt(0)" ::: "memory");
      __builtin_amdgcn_s_barrier();
      if (t + 2 < nIter) {
        const int b2 = (bcur + 2 >= 3) ? bcur - 1 : bcur + 2;  // (bcur+2)%3
        stage(j0, t + 2, b2);
      }
      const char* Ab = (const char*)sm + bcur * TILE3;
      const char* Bb = Ab + 16384;
      if (t == 0) { rdA(a0, Ab, 0); rdB(b0, Bb, 0); }

      // ---- half 0: prefetch half 1 into (a1,b1), MFMA with (a0,b0) ----
      rdA(a1, Ab, 1); rdB(b1, Bb, 1);
#pragma unroll
      for (int mt = 0; mt < 4; ++mt)
#pragma unroll
        for (int nt = 0; nt < 8; ++nt)
          acc[mt][nt] = __builtin_amdgcn_mfma_f32_16x16x32_bf16(
              a0[mt], b0[nt], acc[mt][nt], 0, 0, 0);

      // ---- half 1: prefetch next tile's half 0 into (a0,b0), MFMA with (a1,b1) ----
      const int bn = (bcur + 1 >= 3) ? 0 : bcur + 1;
      if (t + 1 < nIter) {
        const char* An = (const char*)sm + bn * TILE3;
        rdA(a0, An, 0); rdB(b0, An + 16384, 0);
      }
#pragma unroll
      for (int mt = 0; mt < 4; ++mt)
#pragma unroll
        for (int nt = 0; nt < 8; ++nt)
          acc[mt][nt] = __builtin_amdgcn_mfma_f32_16x16x32_bf16(
              a1[mt], b1[nt], acc[mt][nt], 0, 0, 0);

      bcur = bn;
    }

    // Epilogue: out = fe[j] - DT*acc.
#pragma unroll
    for (int mt = 0; mt < 4; ++mt) {
      const int jb = j0 + wr * 64 + mt * 16 + hi4 * 4;
      const float4 fev = *reinterpret_cast<const float4*>(&fe[jb]);
      const float fes[4] = {fev.x, fev.y, fev.z, fev.w};
#pragma unroll
      for (int nt = 0; nt < 8; ++nt) {
        const int i = i0 + wcol * 128 + nt * 16 + lo16;
#pragma unroll
        for (int r = 0; r < 4; ++r) {
          out[(size_t)(jb + r) * M + i] = fmaf(-DT, acc[mt][nt][r], fes[r]);
        }
      }
    }
    __syncthreads();  // all waves' LDS reads retired before next phase restages
  }
}

extern "C" void kernel_launch(void* const* d_in, const int* in_sizes, int n_in,
                              void* d_out, int out_size, void* d_ws, size_t ws_size,
                              hipStream_t stream) {
  const float* x  = (const float*)d_in[0];
  const float* fe = (const float*)d_in[1];
  const float* h  = (const float*)d_in[2];
  float* out = (float*)d_out;

  const size_t matBytes = (size_t)N * N * sizeof(unsigned short);  // 32 MiB
  if (ws_size < 2 * matBytes) return;

  unsigned short* kbT = (unsigned short*)d_ws;
  unsigned short* Tm  = (unsigned short*)((char*)d_ws + matBytes);

  prep_kernel<<<8192, 256, 0, stream>>>(x, h, kbT, Tm);
  gemm_tri_kernel<<<dim3(M / BNW, 16), 256, 0, stream>>>(Tm, kbT, fe, out);
}

// Round 8
// 186.125 us; speedup vs baseline: 1.0918x; 1.0918x over previous
//
#include <hip/hip_runtime.h>
#include <cstdint>
#include <cstddef>

#define N 4096
#define M 4096
#define DT 0.01f

#define BM 128
#define BN 128
#define BK 64   // K elements staged per barrier pair (2 MFMA half-phases)

typedef short bf16x8 __attribute__((ext_vector_type(8)));
typedef float f32x4 __attribute__((ext_vector_type(4)));

__device__ __forceinline__ unsigned short f2bf(float f) {
  unsigned u = __builtin_bit_cast(unsigned, f);
  return (unsigned short)((u + 0x7fffu + ((u >> 16) & 1u)) >> 16);  // RNE
}

// Fused prep. Blocks [0,4096): exp-transpose tiles -> kbT[i*N+l]=bf16(exp(-x[l*M+i])).
// Blocks [4096,8192): weighted Toeplitz row j: Tm[j*N+l] = w*h[j-l] (l<=j else 0),
// w = 1 + 0.5*[l==j] - 0.5*[l==0]   =>   out = fe[j] - dt*(Tm @ k)[j,i].
// Round-8 change: fully-coalesced global stores in BOTH modes.
//  - mode A readout: 8 lanes cover one full 128-B row of kbT (was 4-lane 64-B segments).
//  - mode B: each thread packs 8 CONTIGUOUS elements -> lane-contiguous uint4 stores
//    (was 16-B stores at 32-B lane stride, half-coalesced).
__global__ __launch_bounds__(256)
void prep_kernel(const float* __restrict__ x, const float* __restrict__ h,
                 unsigned short* __restrict__ kbT, unsigned short* __restrict__ Tm) {
  __shared__ __align__(16) unsigned short smem[64 * 66];  // 8448 B, both modes
  const int bid = (int)blockIdx.x;
  const int tid = threadIdx.x;

  if (bid < 4096) {
    // ---- exp-transpose 64x64 tile ----
    unsigned short (*tileT)[66] = (unsigned short(*)[66])smem;  // [i][l]
    const int i0 = (bid & 63) * 64, l0 = (bid >> 6) * 64;
    const int ci = (tid & 15) * 4;
    const int r0 = tid >> 4;
#pragma unroll
    for (int rr = 0; rr < 4; ++rr) {
      const int l = l0 + r0 + rr * 16;
      const float4 xv = *reinterpret_cast<const float4*>(&x[(size_t)l * M + i0 + ci]);
      const int lr = r0 + rr * 16;
      tileT[ci + 0][lr] = f2bf(__expf(-xv.x));
      tileT[ci + 1][lr] = f2bf(__expf(-xv.y));
      tileT[ci + 2][lr] = f2bf(__expf(-xv.z));
      tileT[ci + 3][lr] = f2bf(__expf(-xv.w));
    }
    __syncthreads();
    // Coalesced readout: lanes (ch=tid&7) cover one 128-B row contiguously;
    // LDS bank = (ir + 4*ch) % 32 -> max 2-way (free).
    const int ch = tid & 7;
#pragma unroll
    for (int s = 0; s < 2; ++s) {
      const int ir = (tid >> 3) + s * 32;
      bf16x8 v = *reinterpret_cast<const bf16x8*>(&tileT[ir][ch * 8]);
      *reinterpret_cast<bf16x8*>(&kbT[(size_t)(i0 + ir) * N + l0 + ch * 8]) = v;
    }
  } else {
    // ---- Toeplitz row j ----
    const int j = bid - 4096;
    unsigned short* hb = smem;  // hb[0..4095] = bf16(h[.])
#pragma unroll
    for (int p = 0; p < 4; ++p) {
      const int idx = p * 1024 + tid * 4;
      const float4 hv = *reinterpret_cast<const float4*>(&h[idx]);
      ushort4 pk;
      pk.x = f2bf(hv.x); pk.y = f2bf(hv.y); pk.z = f2bf(hv.z); pk.w = f2bf(hv.w);
      *reinterpret_cast<ushort4*>(&hb[idx]) = pk;
    }
    __syncthreads();
    // Each pass: thread tid owns elements [pass*2048 + tid*8, +8) -> one uint4
    // store, lane-contiguous across the wave (1 KB per wave per instruction).
#pragma unroll
    for (int pass = 0; pass < 2; ++pass) {
      const int lb = pass * 2048 + tid * 8;
      unsigned short v[8];
#pragma unroll
      for (int s = 0; s < 8; ++s) {
        const int l = lb + s;
        unsigned short r = 0;
        if (l <= j) {
          const float w = 1.0f + (l == j ? 0.5f : 0.0f) - (l == 0 ? 0.5f : 0.0f);
          float hv = __builtin_bit_cast(float, (unsigned)hb[j - l] << 16);
          r = f2bf(w * hv);
        }
        v[s] = r;
      }
      uint4 pk;
      pk.x = (unsigned)v[0] | ((unsigned)v[1] << 16);
      pk.y = (unsigned)v[2] | ((unsigned)v[3] << 16);
      pk.z = (unsigned)v[4] | ((unsigned)v[5] << 16);
      pk.w = (unsigned)v[6] | ((unsigned)v[7] << 16);
      *reinterpret_cast<uint4*>(&Tm[(size_t)j * N + lb]) = pk;
    }
  }
}

__device__ __forceinline__ void gld16(void* lds, const void* g) {
  __builtin_amdgcn_global_load_lds(
      (const __attribute__((address_space(1))) void*)g,
      (__attribute__((address_space(3))) void*)lds, 16, 0, 0);
}

// Paired triangular GEMM, BK=64, DOUBLE-BUFFERED LDS with split barriers:
// stage(t+1) is issued BEFORE waiting on tile t; s_waitcnt vmcnt(8) waits only
// the 8 oldest gld16 (tile t), leaving tile t+1's 8 in flight across s_barrier.
// LDS: As0|As1|Bs0|Bs1, 16 KB each = 64 KB -> 2 blocks/CU. The two co-resident
// blocks are INDEPENDENT barrier groups: one computes while the other drains
// staging (m114 wave-level overlap) -- this is the measured-fastest structure
// (77 us; every 1-block/CU redesign measured 88-100 us). Do not collapse to
// one barrier group.
__global__ __launch_bounds__(256)
void gemm_tri_kernel(const unsigned short* __restrict__ Tm,
                     const unsigned short* __restrict__ Bt,
                     const float* __restrict__ fe,
                     float* __restrict__ out) {
  __shared__ __align__(16) unsigned short sm[4 * 8192];  // 64 KB

  const int tid = threadIdx.x;
  const int wave = tid >> 6, lane = tid & 63;
  const int wr = wave >> 1, wc = wave & 1;
  const int lo16 = lane & 15, hi4 = lane >> 4;
  const int i0 = blockIdx.x * BN;
  const int p = (int)blockIdx.y;
  const int sw = lo16 & 7;  // read swizzle key (== row&7 for this lane's rows)

  const size_t strideB = (size_t)N * 2;  // 8192 B per matrix row

  // staging: chunk c = pp*256+tid; row=c>>3, phys chunk=c&7, global chunk=(c&7)^(row&7)
  const int srow = tid >> 3;
  const int gq = ((tid & 7) ^ (srow & 7)) * 16;

  // 8 gld16 per wave per stage: A (4 passes) + B (4 passes) interleaved
  auto stage = [&](int j0s, int t, int buf) {
    const char* Abase = (const char*)Tm + (size_t)j0s * strideB + (size_t)t * 128;
    const char* Bbase = (const char*)Bt + (size_t)i0 * strideB + (size_t)t * 128;
    char* AsB = (char*)sm + buf * 16384;
    char* BsB = (char*)sm + 32768 + buf * 16384;
#pragma unroll
    for (int pp = 0; pp < 4; ++pp) {
      gld16(AsB + pp * 4096 + wave * 1024,
            Abase + (size_t)(srow + pp * 32) * strideB + gq);
      gld16(BsB + pp * 4096 + wave * 1024,
            Bbase + (size_t)(srow + pp * 32) * strideB + gq);
    }
  };

#pragma unroll 1
  for (int ph = 0; ph < 2; ++ph) {
    const int by = ph ? (31 - p) : p;
    const int j0 = by * BM;
    const int nIter = 2 * by + 2;  // 64K causal bound

    f32x4 acc[4][4] = {};

    stage(j0, 0, 0);  // prologue

#pragma unroll 1
    for (int t = 0; t < nIter; ++t) {
      const int cur = t & 1;
      if (t + 1 < nIter) {
        stage(j0, t + 1, cur ^ 1);
        asm volatile("s_waitcnt vmcnt(8)" ::: "memory");  // tile t landed; t+1 in flight
      } else {
        asm volatile("s_waitcnt vmcnt(0)" ::: "memory");  // last tile: full drain
      }
      __builtin_amdgcn_s_barrier();

      const char* AsC = (const char*)sm + cur * 16384;
      const char* BsC = (const char*)sm + 32768 + cur * 16384;
#pragma unroll
      for (int h2 = 0; h2 < 2; ++h2) {
        bf16x8 af[4], bfr[4];
#pragma unroll
        for (int mt = 0; mt < 4; ++mt) {
          const int row = wr * 64 + mt * 16 + lo16;
          const int q = (h2 * 4 + hi4) ^ sw;
          af[mt] = *reinterpret_cast<const bf16x8*>(AsC + row * 128 + q * 16);
        }
#pragma unroll
        for (int nt = 0; nt < 4; ++nt) {
          const int row = wc * 64 + nt * 16 + lo16;
          const int q = (h2 * 4 + hi4) ^ sw;
          bfr[nt] = *reinterpret_cast<const bf16x8*>(BsC + row * 128 + q * 16);
        }
#pragma unroll
        for (int mt = 0; mt < 4; ++mt) {
#pragma unroll
          for (int nt = 0; nt < 4; ++nt) {
            acc[mt][nt] = __builtin_amdgcn_mfma_f32_16x16x32_bf16(
                af[mt], bfr[nt], acc[mt][nt], 0, 0, 0);
          }
        }
      }
      __builtin_amdgcn_s_barrier();  // all reads of buf `cur` done before next overwrite
    }

    // Epilogue: plain stores, out = fe[j] - DT*acc.
#pragma unroll
    for (int mt = 0; mt < 4; ++mt) {
      const int jb = j0 + wr * 64 + mt * 16 + hi4 * 4;
      const float4 fev = *reinterpret_cast<const float4*>(&fe[jb]);
      const float fes[4] = {fev.x, fev.y, fev.z, fev.w};
#pragma unroll
      for (int nt = 0; nt < 4; ++nt) {
        const int i = i0 + wc * 64 + nt * 16 + lo16;
#pragma unroll
        for (int r = 0; r < 4; ++r) {
          out[(size_t)(jb + r) * M + i] = fmaf(-DT, acc[mt][nt][r], fes[r]);
        }
      }
    }
  }
}

extern "C" void kernel_launch(void* const* d_in, const int* in_sizes, int n_in,
                              void* d_out, int out_size, void* d_ws, size_t ws_size,
                              hipStream_t stream) {
  const float* x  = (const float*)d_in[0];
  const float* fe = (const float*)d_in[1];
  const float* h  = (const float*)d_in[2];
  float* out = (float*)d_out;

  const size_t matBytes = (size_t)N * N * sizeof(unsigned short);  // 32 MiB
  if (ws_size < 2 * matBytes) return;

  unsigned short* kbT = (unsigned short*)d_ws;
  unsigned short* Tm  = (unsigned short*)((char*)d_ws + matBytes);

  prep_kernel<<<8192, 256, 0, stream>>>(x, h, kbT, Tm);
  gemm_tri_kernel<<<dim3(M / BN, 16), 256, 0, stream>>>(Tm, kbT, fe, out);
}